// Round 1
// baseline (272.126 us; speedup 1.0000x reference)
//
#include <hip/hip_runtime.h>
#include <cstdint>

#define D_EDGES 64
#define K_KEEP  32

typedef unsigned long long ull;

// Bit-exact replication of numpy's SIMD f32 exp (Cephes-based, max ULP 2.52).
// Verified: absmax 0 vs the np reference in a previous round.
__device__ __forceinline__ float np_expf(float x) {
    const float log2e     = 1.44269504088896341f;
    const float cvt_magic = 12582912.0f;            // 1.5 * 2^23 RNE trick
    const float neg_ln2hi = -0.693359375f;
    const float neg_ln2lo = 2.12194440e-4f;
    const float p0 = 1.9875691500E-4f;
    const float p1 = 1.3981999507E-3f;
    const float p2 = 8.3334519073E-3f;
    const float p3 = 4.1665795894E-2f;
    const float p4 = 1.6666665459E-1f;
    const float p5 = 5.0000001201E-1f;

    float q = fmaf(x, log2e, cvt_magic);
    q -= cvt_magic;
    x = fmaf(q, neg_ln2hi, x);
    x = fmaf(q, neg_ln2lo, x);
    float x2 = x * x;
    float poly = fmaf(p0, x, p1);
    poly = fmaf(poly, x, p2);
    poly = fmaf(poly, x, p3);
    poly = fmaf(poly, x, p4);
    poly = fmaf(poly, x, p5);
    poly = fmaf(poly, x2, x);
    poly = poly + 1.0f;
    return ldexpf(poly, (int)q);
}

__device__ __forceinline__ float sigmoid_np(float x) {
    float e = np_expf(-x);
    return 1.0f / (1.0f + e);
}

__global__ void sigmoid_kernel(const float* __restrict__ logits,
                               float* __restrict__ s, int n) {
    int i = blockIdx.x * blockDim.x + threadIdx.x;
    if (i < n) s[i] = sigmoid_np(logits[i]);
}

// ---- xor-shuffles of a u64 at lane distances 1,2,4,8 ----
// All communication stays inside a 16-lane group (one segment), so only
// quad_perm / row_ror DPP and one ds_swizzle pattern are ever needed.
template <int CTRL>
__device__ __forceinline__ ull xor_dpp_u64(ull v) {
    int lo = (int)(unsigned)v;
    int hi = (int)(v >> 32);
    lo = __builtin_amdgcn_update_dpp(lo, lo, CTRL, 0xF, 0xF, true);
    hi = __builtin_amdgcn_update_dpp(hi, hi, CTRL, 0xF, 0xF, true);
    return ((ull)(unsigned)hi << 32) | (unsigned)lo;
}

__device__ __forceinline__ ull xor4_swz_u64(ull v) {
    int lo = (int)(unsigned)v;
    int hi = (int)(v >> 32);
    lo = __builtin_amdgcn_ds_swizzle(lo, 0x101F);   // xor4 (BitMode)
    hi = __builtin_amdgcn_ds_swizzle(hi, 0x101F);
    return ((ull)(unsigned)hi << 32) | (unsigned)lo;
}

template <int DIST>
__device__ __forceinline__ ull lane_xor_u64(ull v) {
    if constexpr (DIST == 1)      return xor_dpp_u64<0xB1>(v);   // quad_perm [1,0,3,2]
    else if constexpr (DIST == 2) return xor_dpp_u64<0x4E>(v);   // quad_perm [2,3,0,1]
    else if constexpr (DIST == 4) return xor4_swz_u64(v);        // ds_swizzle xor4
    else                          return xor_dpp_u64<0x128>(v);  // row_ror:8 == xor8
}

// ---- 64-element bitonic sort, 4 elements per lane (elem e = 4*t + slot) ----
// Semantics identical to the verified 1-elem/lane network with lane -> e
// substituted:  up = (e&K)==0, isLower = (e&J)==0, descending overall.

// In-lane compare-exchange between slots holding elems 4t+S1 (lower) and its
// partner (J in {1,2}).  'up' constant-folds where (4t+S1)&K is t-invariant.
template <int K, int S1>
__device__ __forceinline__ void lce(ull& ka, ull& kb, int t) {
    bool up = (((4 * t + S1) & K) == 0);
    bool mf = ka > kb;
    if (mf != up) { ull tmp = ka; ka = kb; kb = tmp; }
}

// Cross-lane compare-exchange, elem distance J (>=4), slot S.
template <int K, int J, int S>
__device__ __forceinline__ void cce(ull& k, int t) {
    ull other = lane_xor_u64<J / 4>(k);
    int e = 4 * t + S;
    bool up  = ((e & K) == 0);
    bool low = ((e & J) == 0);
    bool mf  = k > other;
    if (mf != (low == up)) k = other;
}

template <int K, int J>
__device__ __forceinline__ void cce4(ull& k0, ull& k1, ull& k2, ull& k3, int t) {
    cce<K, J, 0>(k0, t);
    cce<K, J, 1>(k1, t);
    cce<K, J, 2>(k2, t);
    cce<K, J, 3>(k3, t);
}

template <int K>
__device__ __forceinline__ void lceJ1(ull& k0, ull& k1, ull& k2, ull& k3, int t) {
    lce<K, 0>(k0, k1, t);      // elems (4t+0, 4t+1)
    lce<K, 2>(k2, k3, t);      // elems (4t+2, 4t+3)
}

template <int K>
__device__ __forceinline__ void lceJ2(ull& k0, ull& k1, ull& k2, ull& k3, int t) {
    lce<K, 0>(k0, k2, t);      // elems (4t+0, 4t+2)
    lce<K, 1>(k1, k3, t);      // elems (4t+1, 4t+3)
}

// Key layout (54 significant bits):
//   [63:34] simbits  (f32 bits of sim in (0,1], <= 0x3F800000: 30 bits, monotone)
//   [33:28] e ^ 63   (ties -> lower original index first under descending sort,
//                     jax.lax.top_k semantics — same scheme as the verified kernel)
//   [27:0]  src      (payload; never reaches the comparator since e is unique)
__device__ __forceinline__ ull make_key(float sim, int e, int src) {
    unsigned sb  = __float_as_uint(sim);
    unsigned e63 = (unsigned)(e ^ 63);
    unsigned hi  = (sb << 2) | (e63 >> 4);
    unsigned lo  = (e63 << 28) | (unsigned)src;
    return ((ull)hi << 32) | lo;
}

// 4 segments per wave: segment = 16-lane group q = lane>>4, t = lane&15.
// Each lane owns elems 4t..4t+3 of its segment.  After the descending sort,
// rank p lives at (t = p>>2, slot = p&3), so ranks 0..31 sit in t < 8.
// dst is constant within a segment (edges grouped by dest — problem invariant),
// so only one dst word is read per segment.
template <bool USE_TABLE>
__global__ void __launch_bounds__(256)
topk_kernel(const int* __restrict__ edge_index,   // [2, E]
            const float* __restrict__ s,
            const float* __restrict__ logits,
            int* __restrict__ out,                // [2, nseg*K]
            long long E, long long nseg) {
    long long gtid = (long long)blockIdx.x * blockDim.x + threadIdx.x;
    long long w = gtid >> 6;
    int lane = (int)(gtid & 63);
    int q = lane >> 4;
    int t = lane & 15;
    long long g = w * 4 + q;                 // segment id (whole group uniform)
    if (g >= nseg) return;

    int4 sv = *reinterpret_cast<const int4*>(edge_index + g * D_EDGES + 4 * t);
    int dstv = edge_index[E + g * D_EDGES];  // one word per segment (broadcast)

    float sd, ss0, ss1, ss2, ss3;
    if constexpr (USE_TABLE) {
        sd  = s[dstv];
        ss0 = s[sv.x]; ss1 = s[sv.y]; ss2 = s[sv.z]; ss3 = s[sv.w];
    } else {
        sd  = sigmoid_np(logits[dstv]);
        ss0 = sigmoid_np(logits[sv.x]);
        ss1 = sigmoid_np(logits[sv.y]);
        ss2 = sigmoid_np(logits[sv.z]);
        ss3 = sigmoid_np(logits[sv.w]);
    }

    ull k0 = make_key(1.0f - fabsf(ss0 - sd), 4 * t + 0, sv.x);
    ull k1 = make_key(1.0f - fabsf(ss1 - sd), 4 * t + 1, sv.y);
    ull k2 = make_key(1.0f - fabsf(ss2 - sd), 4 * t + 2, sv.z);
    ull k3 = make_key(1.0f - fabsf(ss3 - sd), 4 * t + 3, sv.w);

    // 21 substages; 10 in-lane (no shuffle), 8 quad/ror DPP, 2 ds_swizzle.
    lceJ1<2>(k0, k1, k2, k3, t);
    lceJ2<4>(k0, k1, k2, k3, t);   lceJ1<4>(k0, k1, k2, k3, t);
    cce4<8, 4>(k0, k1, k2, k3, t);
    lceJ2<8>(k0, k1, k2, k3, t);   lceJ1<8>(k0, k1, k2, k3, t);
    cce4<16, 8>(k0, k1, k2, k3, t);
    cce4<16, 4>(k0, k1, k2, k3, t);
    lceJ2<16>(k0, k1, k2, k3, t);  lceJ1<16>(k0, k1, k2, k3, t);
    cce4<32, 16>(k0, k1, k2, k3, t);
    cce4<32, 8>(k0, k1, k2, k3, t);
    cce4<32, 4>(k0, k1, k2, k3, t);
    lceJ2<32>(k0, k1, k2, k3, t);  lceJ1<32>(k0, k1, k2, k3, t);
    cce4<64, 32>(k0, k1, k2, k3, t);
    cce4<64, 16>(k0, k1, k2, k3, t);
    cce4<64, 8>(k0, k1, k2, k3, t);
    cce4<64, 4>(k0, k1, k2, k3, t);
    lceJ2<64>(k0, k1, k2, k3, t);  lceJ1<64>(k0, k1, k2, k3, t);

    if (t < 8) {
        long long base = g * K_KEEP + 4 * t;
        int4 r0;
        r0.x = (int)(k0 & 0x0FFFFFFFu);
        r0.y = (int)(k1 & 0x0FFFFFFFu);
        r0.z = (int)(k2 & 0x0FFFFFFFu);
        r0.w = (int)(k3 & 0x0FFFFFFFu);
        *reinterpret_cast<int4*>(out + base) = r0;                    // row 0: src
        *reinterpret_cast<int4*>(out + nseg * K_KEEP + base) =
            make_int4(dstv, dstv, dstv, dstv);                        // row 1: dst
    }
}

extern "C" void kernel_launch(void* const* d_in, const int* in_sizes, int n_in,
                              void* d_out, int out_size, void* d_ws, size_t ws_size,
                              hipStream_t stream) {
    const float* logits = (const float*)d_in[0];
    const int* edge_index = (const int*)d_in[1];
    int N = in_sizes[0];
    long long E = (long long)in_sizes[1] / 2;
    long long nseg = E / D_EDGES;
    int* out = (int*)d_out;

    long long nwave = (nseg + 3) / 4;            // 4 segments per wave
    long long total_threads = nwave * 64;
    int blocks = (int)((total_threads + 255) / 256);

    if (ws_size >= (size_t)N * sizeof(float)) {
        float* s = (float*)d_ws;
        sigmoid_kernel<<<(N + 255) / 256, 256, 0, stream>>>(logits, s, N);
        topk_kernel<true><<<blocks, 256, 0, stream>>>(edge_index, s, logits, out, E, nseg);
    } else {
        topk_kernel<false><<<blocks, 256, 0, stream>>>(edge_index, nullptr, logits, out, E, nseg);
    }
}

// Round 2
// 249.332 us; speedup vs baseline: 1.0914x; 1.0914x over previous
//
#include <hip/hip_runtime.h>
#include <cstdint>

#define D_EDGES 64
#define K_KEEP  32

typedef unsigned long long ull;
typedef int v4i __attribute__((ext_vector_type(4)));

// Bit-exact replication of numpy's SIMD f32 exp (Cephes-based, max ULP 2.52).
// Verified: absmax 0 vs the np reference in a previous round.
__device__ __forceinline__ float np_expf(float x) {
    const float log2e     = 1.44269504088896341f;
    const float cvt_magic = 12582912.0f;            // 1.5 * 2^23 RNE trick
    const float neg_ln2hi = -0.693359375f;
    const float neg_ln2lo = 2.12194440e-4f;
    const float p0 = 1.9875691500E-4f;
    const float p1 = 1.3981999507E-3f;
    const float p2 = 8.3334519073E-3f;
    const float p3 = 4.1665795894E-2f;
    const float p4 = 1.6666665459E-1f;
    const float p5 = 5.0000001201E-1f;

    float q = fmaf(x, log2e, cvt_magic);
    q -= cvt_magic;
    x = fmaf(q, neg_ln2hi, x);
    x = fmaf(q, neg_ln2lo, x);
    float x2 = x * x;
    float poly = fmaf(p0, x, p1);
    poly = fmaf(poly, x, p2);
    poly = fmaf(poly, x, p3);
    poly = fmaf(poly, x, p4);
    poly = fmaf(poly, x, p5);
    poly = fmaf(poly, x2, x);
    poly = poly + 1.0f;
    return ldexpf(poly, (int)q);
}

__device__ __forceinline__ float sigmoid_np(float x) {
    float e = np_expf(-x);
    return 1.0f / (1.0f + e);
}

__global__ void sigmoid_kernel(const float* __restrict__ logits,
                               float* __restrict__ s, int n) {
    int i = blockIdx.x * blockDim.x + threadIdx.x;
    if (i < n) s[i] = sigmoid_np(logits[i]);
}

// Agent-scope relaxed load: compiler-managed, bypasses the (non-agent-coherent)
// per-CU L1 on CDNA. Used for the random table gathers, whose working set (1MB)
// can never hit the 32KB L1 anyway — the L1 miss path is the suspected wall.
__device__ __forceinline__ float gather_agent(const float* p) {
    return __hip_atomic_load(p, __ATOMIC_RELAXED, __HIP_MEMORY_SCOPE_AGENT);
}

// ---- xor-shuffles of a u64 at lane distances 1,2,4,8 ----
template <int CTRL>
__device__ __forceinline__ ull xor_dpp_u64(ull v) {
    int lo = (int)(unsigned)v;
    int hi = (int)(v >> 32);
    lo = __builtin_amdgcn_update_dpp(lo, lo, CTRL, 0xF, 0xF, true);
    hi = __builtin_amdgcn_update_dpp(hi, hi, CTRL, 0xF, 0xF, true);
    return ((ull)(unsigned)hi << 32) | (unsigned)lo;
}

__device__ __forceinline__ ull xor4_swz_u64(ull v) {
    int lo = (int)(unsigned)v;
    int hi = (int)(v >> 32);
    lo = __builtin_amdgcn_ds_swizzle(lo, 0x101F);   // xor4 (BitMode)
    hi = __builtin_amdgcn_ds_swizzle(hi, 0x101F);
    return ((ull)(unsigned)hi << 32) | (unsigned)lo;
}

template <int DIST>
__device__ __forceinline__ ull lane_xor_u64(ull v) {
    if constexpr (DIST == 1)      return xor_dpp_u64<0xB1>(v);   // quad_perm [1,0,3,2]
    else if constexpr (DIST == 2) return xor_dpp_u64<0x4E>(v);   // quad_perm [2,3,0,1]
    else if constexpr (DIST == 4) return xor4_swz_u64(v);        // ds_swizzle xor4
    else                          return xor_dpp_u64<0x128>(v);  // row_ror:8 == xor8
}

// ---- 64-element bitonic sort, 4 elements per lane (elem e = 4*t + slot) ----
template <int K, int S1>
__device__ __forceinline__ void lce(ull& ka, ull& kb, int t) {
    bool up = (((4 * t + S1) & K) == 0);
    bool mf = ka > kb;
    if (mf != up) { ull tmp = ka; ka = kb; kb = tmp; }
}

template <int K, int J, int S>
__device__ __forceinline__ void cce(ull& k, int t) {
    ull other = lane_xor_u64<J / 4>(k);
    int e = 4 * t + S;
    bool up  = ((e & K) == 0);
    bool low = ((e & J) == 0);
    bool mf  = k > other;
    if (mf != (low == up)) k = other;
}

template <int K, int J>
__device__ __forceinline__ void cce4(ull& k0, ull& k1, ull& k2, ull& k3, int t) {
    cce<K, J, 0>(k0, t);
    cce<K, J, 1>(k1, t);
    cce<K, J, 2>(k2, t);
    cce<K, J, 3>(k3, t);
}

template <int K>
__device__ __forceinline__ void lceJ1(ull& k0, ull& k1, ull& k2, ull& k3, int t) {
    lce<K, 0>(k0, k1, t);
    lce<K, 2>(k2, k3, t);
}

template <int K>
__device__ __forceinline__ void lceJ2(ull& k0, ull& k1, ull& k2, ull& k3, int t) {
    lce<K, 0>(k0, k2, t);
    lce<K, 1>(k1, k3, t);
}

// Key layout (54 significant bits):
//   [63:34] simbits  [33:28] e^63 (tie -> lower index)  [27:0] src payload
__device__ __forceinline__ ull make_key(float sim, int e, int src) {
    unsigned sb  = __float_as_uint(sim);
    unsigned e63 = (unsigned)(e ^ 63);
    unsigned hi  = (sb << 2) | (e63 >> 4);
    unsigned lo  = (e63 << 28) | (unsigned)src;
    return ((ull)hi << 32) | lo;
}

// 4 segments per wave; segment = 16-lane group q, t = lane&15; lane owns
// elems 4t..4t+3. After descending sort, rank p is at (t=p>>2, slot=p&3).
// dst is constant within a segment (edges grouped by dest — problem invariant).
template <bool USE_TABLE>
__global__ void __launch_bounds__(256)
topk_kernel(const int* __restrict__ edge_index,   // [2, E]
            const float* __restrict__ s,
            const float* __restrict__ logits,
            int* __restrict__ out,                // [2, nseg*K]
            long long E, long long nseg) {
    long long gtid = (long long)blockIdx.x * blockDim.x + threadIdx.x;
    long long w = gtid >> 6;
    int lane = (int)(gtid & 63);
    int q = lane >> 4;
    int t = lane & 15;
    long long g = w * 4 + q;                 // segment id
    if (g >= nseg) return;

    // Streaming data: nontemporal (evict-first) so the 1MB gather table
    // keeps its L2 residency against the two 67MB streams.
    v4i sv = __builtin_nontemporal_load(
        reinterpret_cast<const v4i*>(edge_index + g * D_EDGES + 4 * t));
    int dstv = edge_index[E + g * D_EDGES];  // one word per segment (broadcast)

    float sd, ss0, ss1, ss2, ss3;
    if constexpr (USE_TABLE) {
        sd  = s[dstv];
        ss0 = gather_agent(s + sv.x);
        ss1 = gather_agent(s + sv.y);
        ss2 = gather_agent(s + sv.z);
        ss3 = gather_agent(s + sv.w);
    } else {
        sd  = sigmoid_np(logits[dstv]);
        ss0 = sigmoid_np(gather_agent(logits + sv.x));
        ss1 = sigmoid_np(gather_agent(logits + sv.y));
        ss2 = sigmoid_np(gather_agent(logits + sv.z));
        ss3 = sigmoid_np(gather_agent(logits + sv.w));
    }

    ull k0 = make_key(1.0f - fabsf(ss0 - sd), 4 * t + 0, sv.x);
    ull k1 = make_key(1.0f - fabsf(ss1 - sd), 4 * t + 1, sv.y);
    ull k2 = make_key(1.0f - fabsf(ss2 - sd), 4 * t + 2, sv.z);
    ull k3 = make_key(1.0f - fabsf(ss3 - sd), 4 * t + 3, sv.w);

    // 21 substages; 10 in-lane (no shuffle), 8 quad/ror DPP, 2 ds_swizzle.
    lceJ1<2>(k0, k1, k2, k3, t);
    lceJ2<4>(k0, k1, k2, k3, t);   lceJ1<4>(k0, k1, k2, k3, t);
    cce4<8, 4>(k0, k1, k2, k3, t);
    lceJ2<8>(k0, k1, k2, k3, t);   lceJ1<8>(k0, k1, k2, k3, t);
    cce4<16, 8>(k0, k1, k2, k3, t);
    cce4<16, 4>(k0, k1, k2, k3, t);
    lceJ2<16>(k0, k1, k2, k3, t);  lceJ1<16>(k0, k1, k2, k3, t);
    cce4<32, 16>(k0, k1, k2, k3, t);
    cce4<32, 8>(k0, k1, k2, k3, t);
    cce4<32, 4>(k0, k1, k2, k3, t);
    lceJ2<32>(k0, k1, k2, k3, t);  lceJ1<32>(k0, k1, k2, k3, t);
    cce4<64, 32>(k0, k1, k2, k3, t);
    cce4<64, 16>(k0, k1, k2, k3, t);
    cce4<64, 8>(k0, k1, k2, k3, t);
    cce4<64, 4>(k0, k1, k2, k3, t);
    lceJ2<64>(k0, k1, k2, k3, t);  lceJ1<64>(k0, k1, k2, k3, t);

    if (t < 8) {
        long long base = g * K_KEEP + 4 * t;
        v4i r0;
        r0.x = (int)(k0 & 0x0FFFFFFFu);
        r0.y = (int)(k1 & 0x0FFFFFFFu);
        r0.z = (int)(k2 & 0x0FFFFFFFu);
        r0.w = (int)(k3 & 0x0FFFFFFFu);
        v4i dv;
        dv.x = dstv; dv.y = dstv; dv.z = dstv; dv.w = dstv;
        __builtin_nontemporal_store(r0, reinterpret_cast<v4i*>(out + base));
        __builtin_nontemporal_store(dv, reinterpret_cast<v4i*>(out + nseg * K_KEEP + base));
    }
}

extern "C" void kernel_launch(void* const* d_in, const int* in_sizes, int n_in,
                              void* d_out, int out_size, void* d_ws, size_t ws_size,
                              hipStream_t stream) {
    const float* logits = (const float*)d_in[0];
    const int* edge_index = (const int*)d_in[1];
    int N = in_sizes[0];
    long long E = (long long)in_sizes[1] / 2;
    long long nseg = E / D_EDGES;
    int* out = (int*)d_out;

    long long nwave = (nseg + 3) / 4;            // 4 segments per wave
    long long total_threads = nwave * 64;
    int blocks = (int)((total_threads + 255) / 256);

    if (ws_size >= (size_t)N * sizeof(float)) {
        float* s = (float*)d_ws;
        sigmoid_kernel<<<(N + 255) / 256, 256, 0, stream>>>(logits, s, N);
        topk_kernel<true><<<blocks, 256, 0, stream>>>(edge_index, s, logits, out, E, nseg);
    } else {
        topk_kernel<false><<<blocks, 256, 0, stream>>>(edge_index, nullptr, logits, out, E, nseg);
    }
}